// Round 10
// baseline (595.896 us; speedup 1.0000x reference)
//
#include <hip/hip_runtime.h>
#include <math.h>

// Problem constants (from reference)
#define N_    128
#define T_    1000
#define NS_   10
#define NO_   10
#define HID_  64
#define DENSE_ 32

typedef float v2f __attribute__((ext_vector_type(2)));
typedef float v4f __attribute__((ext_vector_type(4)));
typedef _Float16 h2v __attribute__((ext_vector_type(2)));

// Barrier that waits only on LDS ops (global h_out stores are consumed by a
// later dispatch, never by another wave in-kernel -> no vmcnt drain).
#define LDS_BARRIER() asm volatile("s_waitcnt lgkmcnt(0)\n\ts_barrier" ::: "memory")

// f16 dot2: acc += a[0]*b[0] + a[1]*b[1]  (v_dot2_f32_f16)
#if __has_builtin(__builtin_amdgcn_fdot2)
#define FDOT2(acc, a, b) (acc) = __builtin_amdgcn_fdot2((a), (b), (acc), false)
#else
#define FDOT2(acc, a, b) asm("v_dot2_f32_f16 %0, %1, %2, %0" : "+v"(acc) : "v"(a), "v"(b))
#endif

// pack two f32 -> 2x f16 (v_cvt_pkrtz_f16_f32), bit-cast to our h2v type
__device__ __forceinline__ h2v pk_f16(float a, float b) {
    return __builtin_bit_cast(h2v, __builtin_amdgcn_cvt_pkrtz(a, b));
}

// lane^1 exchange via DPP quad_perm [1,0,3,2] — VALU speed, no LDS
__device__ __forceinline__ float dpp_xor1(float x) {
    int r = __builtin_amdgcn_update_dpp(0, __builtin_bit_cast(int, x),
                                        0xB1, 0xF, 0xF, true);
    return __builtin_bit_cast(float, r);
}

__device__ __forceinline__ float fast_sigmoid(float x) {
    return __builtin_amdgcn_rcpf(1.f + __expf(-x));   // NaN-safe
}
__device__ __forceinline__ float fast_tanh(float x) {
    float e = __expf(2.f * x);
    return 1.f - 2.f * __builtin_amdgcn_rcpf(e + 1.f); // NaN-safe
}

// ---------------------------------------------------------------------------
// Phase 0: A = H^T inv(C_w) (NS x NO), M = A H (NS x NS), out[0] = const term.
// Parallel Gauss-Jordan: row ops spread over threads, syncthreads per pivot.
// ---------------------------------------------------------------------------
__global__ void setup_consts(const float* __restrict__ H,
                             const float* __restrict__ C_w,
                             float* __restrict__ A,   // (NS,NO)
                             float* __restrict__ M,   // (NS,NS)
                             float* __restrict__ out)
{
    __shared__ float W[NO_][2 * NO_];
    __shared__ float fcol[NO_];
    __shared__ float As[NS_][NO_];
    const int tid = threadIdx.x;     // 256
    if (blockIdx.x != 0) return;
    if (tid == 0)
        out[0] = 0.5f * (float)NS_ * (float)T_ * logf(2.f * 3.14159265358979323846f);
    if (tid < NO_ * NO_) {
        const int i = tid / NO_, j = tid % NO_;
        W[i][j] = C_w[tid];
        W[i][NO_ + j] = (i == j) ? 1.f : 0.f;
    }
    __syncthreads();
    for (int p = 0; p < NO_; ++p) {
        const float ip = 1.f / W[p][p];
        __syncthreads();
        if (tid < 2 * NO_) W[p][tid] *= ip;
        __syncthreads();
        if (tid < NO_) fcol[tid] = (tid == p) ? 0.f : W[tid][p];
        __syncthreads();
        if (tid < NO_ * 2 * NO_) {
            const int i = tid / (2 * NO_), j = tid % (2 * NO_);
            W[i][j] -= fcol[i] * W[p][j];
        }
        __syncthreads();
    }
    if (tid < NS_ * NO_) {
        const int s = tid / NO_, o = tid % NO_;
        float acc = 0.f;
        for (int p = 0; p < NO_; ++p) acc += H[p * NS_ + s] * W[p][NO_ + o];
        As[s][o] = acc;
        A[tid] = acc;
    }
    __syncthreads();
    if (tid < NS_ * NS_) {
        const int s = tid / NS_, q = tid % NS_;
        float acc = 0.f;
        for (int o = 0; o < NO_; ++o) acc += As[s][o] * H[o * NS_ + q];
        M[tid] = acc;
    }
}

// ---------------------------------------------------------------------------
// Phase 1: GRU scan, TWO samples per block (weights shared across samples).
// 2 waves; lane pair (2m,2m+1) owns hidden unit j (wave w: j=w*32+m) for all
// three gates, split across K-halves (kh=l&1). Per step, for both samples:
// x-proj f32 | uniform LDS read of prev h (f16, 4xb128 each) | 48x
// v_dot2_f32_f16 each | DPP pair-combine | lane-local sigmoid/tanh | even
// lane publishes h | ONE LDS-only barrier. Sample B's chains fill sample A's
// latency stalls (trans/LDS) — the r9 single-sample structure was ~50%
// exposed-latency.
// ---------------------------------------------------------------------------
__global__ __launch_bounds__(128, 1) void gru_kernel(
    const float* __restrict__ Y,     // (N,T,NO)
    const float* __restrict__ W_ih,  // (192,10)
    const float* __restrict__ W_hh,  // (192,64)
    const float* __restrict__ b_ih,
    const float* __restrict__ b_hh,
    float* __restrict__ h_out)       // (N*T,64)
{
    const int bid = blockIdx.x;      // 0..63
    const int nA  = 2 * bid, nB = nA + 1;
    const int tid = threadIdx.x;     // 0..127
    const int w   = tid >> 6;        // wave 0,1
    const int l   = tid & 63;
    const int j   = w * 32 + (l >> 1);   // hidden unit 0..63
    const int kh  = l & 1;               // K half

    // --- weights (shared by both samples): W_hh K-half f16, W_ih f32 ---
    h2v whh[3][16];
#pragma unroll
    for (int g = 0; g < 3; ++g) {
        const v4f* wp = (const v4f*)(W_hh + (size_t)(g * HID_ + j) * HID_ + kh * 32);
#pragma unroll
        for (int q = 0; q < 8; ++q) {
            v4f t = wp[q];
            whh[g][2 * q]     = pk_f16(t.x, t.y);
            whh[g][2 * q + 1] = pk_f16(t.z, t.w);
        }
    }
    float wih[3][5];
#pragma unroll
    for (int g = 0; g < 3; ++g) {
        const float* ip = W_ih + (size_t)(g * HID_ + j) * NO_ + kh * 5;
#pragma unroll
        for (int i = 0; i < 5; ++i) wih[g][i] = ip[i];
    }
    // VOLATILE pin: cannot be sunk into the loop -> values stay resident.
#pragma unroll
    for (int g = 0; g < 3; ++g) {
#pragma unroll
        for (int k = 0; k < 16; ++k) asm volatile("" : "+v"(whh[g][k]));
#pragma unroll
        for (int i = 0; i < 5; ++i) asm volatile("" : "+v"(wih[g][i]));
    }

    const float bR  = b_ih[j] + b_hh[j];
    const float bZ  = b_ih[HID_ + j] + b_hh[HID_ + j];
    const float bNx = b_ih[2 * HID_ + j];
    const float bNh = b_hh[2 * HID_ + j];

    // double-buffered f16 hidden state per sample (state t in buf[t&1])
    __shared__ __align__(16) _Float16 hAb[2][HID_];
    __shared__ __align__(16) _Float16 hBb[2][HID_];
    if (tid < HID_) hAb[1][tid] = (_Float16)0.f;
    else            hBb[1][tid - HID_] = (_Float16)0.f;
    float hoA = 0.f, hoB = 0.f;
    LDS_BARRIER();

    const float* YkA = Y + (size_t)nA * T_ * NO_ + kh * 5;
    const float* YkB = Y + (size_t)nB * T_ * NO_ + kh * 5;
    float* houtA = h_out + (size_t)nA * T_ * HID_ + j;
    float* houtB = h_out + (size_t)nB * T_ * HID_ + j;

    // depth-2 y prefetch, both samples
    float yA0[5], yA1[5], yB0[5], yB1[5];
#pragma unroll
    for (int i = 0; i < 5; ++i) { yA0[i] = YkA[i]; yA1[i] = YkA[NO_ + i]; }
#pragma unroll
    for (int i = 0; i < 5; ++i) { yB0[i] = YkB[i]; yB1[i] = YkB[NO_ + i]; }

    auto step = [&](int t, float (&yA)[5], float (&yB)[5], int tl) {
        const int p = t & 1;

        // x-projections (f32 registers; hides under LDS-read latency)
        float xrA = 0.f, xzA = 0.f, xnA = 0.f;
        float xrB = 0.f, xzB = 0.f, xnB = 0.f;
#pragma unroll
        for (int i = 0; i < 5; ++i) {
            xrA += wih[0][i] * yA[i]; xzA += wih[1][i] * yA[i]; xnA += wih[2][i] * yA[i];
            xrB += wih[0][i] * yB[i]; xzB += wih[1][i] * yB[i]; xnB += wih[2][i] * yB[i];
        }
        // refill y (used 2 steps from now)
        {
            const float* pa = YkA + (size_t)tl * NO_;
            const float* pb = YkB + (size_t)tl * NO_;
#pragma unroll
            for (int i = 0; i < 5; ++i) { yA[i] = pa[i]; yB[i] = pb[i]; }
        }
        // h-projections: uniform b128 reads of prev state (own K-half)
        float arA = 0.f, azA = 0.f, anA = 0.f;
        float arB = 0.f, azB = 0.f, anB = 0.f;
        const uint4* hpA = (const uint4*)(&hAb[1 - p][kh * 32]);
        const uint4* hpB = (const uint4*)(&hBb[1 - p][kh * 32]);
#pragma unroll
        for (int q = 0; q < 4; ++q) {
            uint4 ha = hpA[q];
            uint4 hb = hpB[q];
            h2v a0 = __builtin_bit_cast(h2v, ha.x), a1 = __builtin_bit_cast(h2v, ha.y);
            h2v a2 = __builtin_bit_cast(h2v, ha.z), a3 = __builtin_bit_cast(h2v, ha.w);
            h2v b0 = __builtin_bit_cast(h2v, hb.x), b1 = __builtin_bit_cast(h2v, hb.y);
            h2v b2 = __builtin_bit_cast(h2v, hb.z), b3 = __builtin_bit_cast(h2v, hb.w);
            FDOT2(arA, whh[0][4*q+0], a0); FDOT2(azA, whh[1][4*q+0], a0); FDOT2(anA, whh[2][4*q+0], a0);
            FDOT2(arB, whh[0][4*q+0], b0); FDOT2(azB, whh[1][4*q+0], b0); FDOT2(anB, whh[2][4*q+0], b0);
            FDOT2(arA, whh[0][4*q+1], a1); FDOT2(azA, whh[1][4*q+1], a1); FDOT2(anA, whh[2][4*q+1], a1);
            FDOT2(arB, whh[0][4*q+1], b1); FDOT2(azB, whh[1][4*q+1], b1); FDOT2(anB, whh[2][4*q+1], b1);
            FDOT2(arA, whh[0][4*q+2], a2); FDOT2(azA, whh[1][4*q+2], a2); FDOT2(anA, whh[2][4*q+2], a2);
            FDOT2(arB, whh[0][4*q+2], b2); FDOT2(azB, whh[1][4*q+2], b2); FDOT2(anB, whh[2][4*q+2], b2);
            FDOT2(arA, whh[0][4*q+3], a3); FDOT2(azA, whh[1][4*q+3], a3); FDOT2(anA, whh[2][4*q+3], a3);
            FDOT2(arB, whh[0][4*q+3], b3); FDOT2(azB, whh[1][4*q+3], b3); FDOT2(anB, whh[2][4*q+3], b3);
        }
        // pair-combine via DPP (lane^1); biases added AFTER (no doubling)
        float srA = xrA + arA;  srA += dpp_xor1(srA);
        float srB = xrB + arB;  srB += dpp_xor1(srB);
        float szA = xzA + azA;  szA += dpp_xor1(szA);
        float szB = xzB + azB;  szB += dpp_xor1(szB);
        float sxA = xnA;        sxA += dpp_xor1(sxA);
        float sxB = xnB;        sxB += dpp_xor1(sxB);
        float shA = anA;        shA += dpp_xor1(shA);
        float shB = anB;        shB += dpp_xor1(shB);
        // gates: A and B chains interleave (B fills A's trans latency)
        const float rA = fast_sigmoid(srA + bR);
        const float rB = fast_sigmoid(srB + bR);
        const float zA = fast_sigmoid(szA + bZ);
        const float zB = fast_sigmoid(szB + bZ);
        const float nnA = fast_tanh(sxA + bNx + rA * (shA + bNh));
        const float nnB = fast_tanh(sxB + bNx + rB * (shB + bNh));
        const float hnA = nnA + zA * (hoA - nnA);
        const float hnB = nnB + zB * (hoB - nnB);
        hoA = hnA; hoB = hnB;
        if (kh == 0) {
            hAb[p][j] = (_Float16)hnA;  houtA[t * HID_] = hnA;
            hBb[p][j] = (_Float16)hnB;  houtB[t * HID_] = hnB;
        }
        LDS_BARRIER();
    };

    for (int t = 0; t < T_; t += 2) {
        const int t2 = (t + 2 < T_) ? t + 2 : T_ - 1;
        const int t3 = (t + 3 < T_) ? t + 3 : T_ - 1;
        step(t,     yA0, yB0, t2);
        step(t + 1, yA1, yB1, t3);
    }
}

// ---------------------------------------------------------------------------
// Phase 2: per-(n,t) dense head + information-form Kalman + log-pdf terms.
// ---------------------------------------------------------------------------
__global__ __launch_bounds__(256) void post_kernel(
    const float* __restrict__ h_out,  // (N*T,64)
    const float* __restrict__ Y,      // (N,T,NO)
    const float* __restrict__ X,      // (N,T,NS)
    const float* __restrict__ W_fc, const float* __restrict__ b_fc,
    const float* __restrict__ W_mean, const float* __restrict__ b_mean,
    const float* __restrict__ W_vars, const float* __restrict__ b_vars,
    const float* __restrict__ Ac,     // (NS,NO)
    const float* __restrict__ Mc,     // (NS,NS)
    float* __restrict__ out)
{
    __shared__ float sWfc[DENSE_][HID_];
    __shared__ float sWm[NS_][DENSE_];
    __shared__ float sWv[NS_][DENSE_];
    __shared__ float sA[NS_][NO_];
    __shared__ float sM[NS_][NS_];
    __shared__ float sbfc[DENSE_], sbm[NS_], sbv[NS_];
    __shared__ float wsum[4];

    for (int i = threadIdx.x; i < DENSE_ * HID_; i += blockDim.x)
        sWfc[i / HID_][i % HID_] = W_fc[i];
    for (int i = threadIdx.x; i < NS_ * DENSE_; i += blockDim.x) {
        sWm[i / DENSE_][i % DENSE_] = W_mean[i];
        sWv[i / DENSE_][i % DENSE_] = W_vars[i];
    }
    for (int i = threadIdx.x; i < NS_ * NO_; i += blockDim.x) sA[i / NO_][i % NO_] = Ac[i];
    for (int i = threadIdx.x; i < NS_ * NS_; i += blockDim.x) sM[i / NS_][i % NS_] = Mc[i];
    if (threadIdx.x < DENSE_) sbfc[threadIdx.x] = b_fc[threadIdx.x];
    if (threadIdx.x < NS_) { sbm[threadIdx.x] = b_mean[threadIdx.x]; sbv[threadIdx.x] = b_vars[threadIdx.x]; }
    __syncthreads();

    const int task = blockIdx.x * blockDim.x + threadIdx.x;
    float contrib = 0.f;
    if (task < N_ * T_) {
        float y[DENSE_];
#pragma unroll
        for (int d = 0; d < DENSE_; ++d) y[d] = sbfc[d];
        const float* hp = h_out + (size_t)task * HID_;
#pragma unroll
        for (int k = 0; k < HID_; k += 4) {
            float4 h4 = *(const float4*)(hp + k);
#pragma unroll
            for (int d = 0; d < DENSE_; ++d) {
                y[d] += sWfc[d][k + 0] * h4.x + sWfc[d][k + 1] * h4.y +
                        sWfc[d][k + 2] * h4.z + sWfc[d][k + 3] * h4.w;
            }
        }
#pragma unroll
        for (int d = 0; d < DENSE_; ++d) y[d] = fmaxf(y[d], 0.f);

        float mu[NS_], vinv[NS_];
#pragma unroll
        for (int s = 0; s < NS_; ++s) {
            float am = sbm[s], av = sbv[s];
#pragma unroll
            for (int d = 0; d < DENSE_; ++d) { am += sWm[s][d] * y[d]; av += sWv[s][d] * y[d]; }
            mu[s] = am;
            float sp = (av > 20.f) ? av : log1pf(__expf(av));  // softplus
            vinv[s] = 1.f / sp;
        }

        const float* yo = Y + (size_t)task * NO_;
        const float* xo = X + (size_t)task * NS_;
        float b[NS_];
#pragma unroll
        for (int s = 0; s < NS_; ++s) {
            float acc = vinv[s] * mu[s];
#pragma unroll
            for (int o = 0; o < NO_; ++o) acc += sA[s][o] * yo[o];
            b[s] = acc;
        }

        // L_inv = M + diag(v^-1), Cholesky
        float L[NS_][NS_];
#pragma unroll
        for (int i = 0; i < NS_; ++i)
#pragma unroll
            for (int jj = 0; jj <= i; ++jj)
                L[i][jj] = sM[i][jj] + ((i == jj) ? vinv[i] : 0.f);
        float ld = 0.f;
        float dinv[NS_];
#pragma unroll
        for (int jj = 0; jj < NS_; ++jj) {
            float s = L[jj][jj];
#pragma unroll
            for (int k = 0; k < jj; ++k) s -= L[jj][k] * L[jj][k];
            float d = sqrtf(s);
            ld += __logf(d);
            float di = 1.f / d;
            dinv[jj] = di;
            L[jj][jj] = d;
#pragma unroll
            for (int i = jj + 1; i < NS_; ++i) {
                float t2 = L[i][jj];
#pragma unroll
                for (int k = 0; k < jj; ++k) t2 -= L[i][k] * L[jj][k];
                L[i][jj] = t2 * di;
            }
        }
        ld *= 2.f;

        float w[NS_];
#pragma unroll
        for (int i = 0; i < NS_; ++i) {
            float s = b[i];
#pragma unroll
            for (int k = 0; k < i; ++k) s -= L[i][k] * w[k];
            w[i] = s * dinv[i];
        }
        float mpost[NS_];
#pragma unroll
        for (int ii = NS_ - 1; ii >= 0; --ii) {
            float s = w[ii];
#pragma unroll
            for (int k = ii + 1; k < NS_; ++k) s -= L[k][ii] * mpost[k];
            mpost[ii] = s * dinv[ii];
        }

        float diff[NS_];
#pragma unroll
        for (int s = 0; s < NS_; ++s) diff[s] = xo[s] - mpost[s];
        float quad = 0.f;
#pragma unroll
        for (int jj = 0; jj < NS_; ++jj) {
            float u = 0.f;
#pragma unroll
            for (int i = jj; i < NS_; ++i) u += L[i][jj] * diff[i];
            quad += u * u;
        }

        contrib = 0.5f * (ld - quad) * (1.0f / (float)N_);
    }

#pragma unroll
    for (int off = 32; off; off >>= 1) contrib += __shfl_down(contrib, off);
    const int wid = threadIdx.x >> 6;
    if ((threadIdx.x & 63) == 0) wsum[wid] = contrib;
    __syncthreads();
    if (threadIdx.x == 0) {
        float s = 0.f;
#pragma unroll
        for (int i = 0; i < 4; ++i) s += wsum[i];
        atomicAdd(out, s);
    }
}

// ---------------------------------------------------------------------------
extern "C" void kernel_launch(void* const* d_in, const int* in_sizes, int n_in,
                              void* d_out, int out_size, void* d_ws, size_t ws_size,
                              hipStream_t stream)
{
    const float* Y      = (const float*)d_in[0];
    const float* X      = (const float*)d_in[1];
    const float* H      = (const float*)d_in[2];
    const float* C_w    = (const float*)d_in[4];
    const float* W_ih   = (const float*)d_in[5];
    const float* W_hh   = (const float*)d_in[6];
    const float* b_ih   = (const float*)d_in[7];
    const float* b_hh   = (const float*)d_in[8];
    const float* W_fc   = (const float*)d_in[9];
    const float* b_fc   = (const float*)d_in[10];
    const float* W_mean = (const float*)d_in[11];
    const float* b_mean = (const float*)d_in[12];
    const float* W_vars = (const float*)d_in[13];
    const float* b_vars = (const float*)d_in[14];
    float* out = (float*)d_out;

    float* h_out = (float*)d_ws;                       // 32.77 MB
    float* Ac = h_out + (size_t)N_ * T_ * HID_;
    float* Mc = Ac + NS_ * NO_;

    hipLaunchKernelGGL(setup_consts, dim3(1), dim3(256), 0, stream, H, C_w, Ac, Mc, out);
    hipLaunchKernelGGL(gru_kernel, dim3(N_ / 2), dim3(128), 0, stream,
                       Y, W_ih, W_hh, b_ih, b_hh, h_out);
    hipLaunchKernelGGL(post_kernel, dim3((N_ * T_ + 255) / 256), dim3(256), 0, stream,
                       h_out, Y, X, W_fc, b_fc, W_mean, b_mean, W_vars, b_vars,
                       Ac, Mc, out);
}

// Round 11
// 495.672 us; speedup vs baseline: 1.2022x; 1.2022x over previous
//
#include <hip/hip_runtime.h>
#include <math.h>

// Problem constants (from reference)
#define N_    128
#define T_    1000
#define NS_   10
#define NO_   10
#define HID_  64
#define DENSE_ 32

typedef float v2f __attribute__((ext_vector_type(2)));
typedef float v4f __attribute__((ext_vector_type(4)));
typedef _Float16 h2v __attribute__((ext_vector_type(2)));

// f16 dot2: acc += a[0]*b[0] + a[1]*b[1]  (v_dot2_f32_f16)
#if __has_builtin(__builtin_amdgcn_fdot2)
#define FDOT2(acc, a, b) (acc) = __builtin_amdgcn_fdot2((a), (b), (acc), false)
#else
#define FDOT2(acc, a, b) asm("v_dot2_f32_f16 %0, %1, %2, %0" : "+v"(acc) : "v"(a), "v"(b))
#endif

// pack two f32 -> 2x f16 (v_cvt_pkrtz_f16_f32), bit-cast to our h2v type
__device__ __forceinline__ h2v pk_f16(float a, float b) {
    return __builtin_bit_cast(h2v, __builtin_amdgcn_cvt_pkrtz(a, b));
}

__device__ __forceinline__ float fast_sigmoid(float x) {
    return __builtin_amdgcn_rcpf(1.f + __expf(-x));   // NaN-safe
}
__device__ __forceinline__ float fast_tanh(float x) {
    float e = __expf(2.f * x);
    return 1.f - 2.f * __builtin_amdgcn_rcpf(e + 1.f); // NaN-safe
}

// ---------------------------------------------------------------------------
// Phase 1: GRU scan. ONE WAVE per sample; lane j owns hidden unit j for all
// three gates (full 64-K dots). Zero barriers: h propagates via same-wave
// in-order LDS (write h[j], later uniformly read all 64 — single 128B buf).
// Weights f16, volatile-pinned (111 VGPRs; launch_bounds(64,1) -> full
// budget; the r2..r6 remat-reload killer stays dead per r7/r9 FETCH).
// Per step: 15 dot2 x-proj | 8 uniform ds_read_b128 of h | 96 dot2 | trans
// chain | h update | ds_write_b16 + fire-and-forget global store.
// Block 0 lane 0 also initializes out[0] with the constant log(2pi) term
// (gru dispatch fully precedes post dispatch -> no race with atomics).
// ---------------------------------------------------------------------------
__global__ __launch_bounds__(64, 1) void gru_kernel(
    const float* __restrict__ Y,     // (N,T,NO)
    const float* __restrict__ W_ih,  // (192,10)
    const float* __restrict__ W_hh,  // (192,64)
    const float* __restrict__ b_ih,
    const float* __restrict__ b_hh,
    float* __restrict__ h_out,       // (N*T,64)
    float* __restrict__ out)
{
    const int n = blockIdx.x;
    const int j = threadIdx.x;       // 0..63, owns hidden unit j

    if (n == 0 && j == 0)
        out[0] = 0.5f * (float)NS_ * (float)T_ * logf(2.f * 3.14159265358979323846f);

    // --- weights: 3 full gate rows of W_hh (f16 pairs) + W_ih (f16 pairs) ---
    h2v whh[3][32];
#pragma unroll
    for (int g = 0; g < 3; ++g) {
        const v4f* wp = (const v4f*)(W_hh + (size_t)(g * HID_ + j) * HID_);
#pragma unroll
        for (int q = 0; q < 16; ++q) {
            v4f t = wp[q];
            whh[g][2 * q]     = pk_f16(t.x, t.y);
            whh[g][2 * q + 1] = pk_f16(t.z, t.w);
        }
    }
    h2v wih[3][5];
#pragma unroll
    for (int g = 0; g < 3; ++g) {
        const v2f* ip = (const v2f*)(W_ih + (size_t)(g * HID_ + j) * NO_);
#pragma unroll
        for (int i = 0; i < 5; ++i) { v2f t = ip[i]; wih[g][i] = pk_f16(t[0], t[1]); }
    }
    // VOLATILE pin: cannot be sunk into the loop -> values stay resident.
#pragma unroll
    for (int g = 0; g < 3; ++g) {
#pragma unroll
        for (int k = 0; k < 32; ++k) asm volatile("" : "+v"(whh[g][k]));
#pragma unroll
        for (int i = 0; i < 5; ++i) asm volatile("" : "+v"(wih[g][i]));
    }

    const float bR  = b_ih[j] + b_hh[j];
    const float bZ  = b_ih[HID_ + j] + b_hh[HID_ + j];
    const float bNx = b_ih[2 * HID_ + j];
    const float bNh = b_hh[2 * HID_ + j];

    // single-buffer f16 hidden state: same-wave DS ops are program-ordered,
    // so write(t) -> read(t+1) -> write(t+1) is race-free with ONE wave.
    __shared__ __align__(16) _Float16 hbuf[HID_];
    hbuf[j] = (_Float16)0.f;
    float h_own = 0.f;

    const float* Yn = Y + (size_t)n * T_ * NO_;
    float* hout = h_out + (size_t)n * T_ * HID_ + j;

    // depth-2 y prefetch (rows packed to f16 pairs)
    h2v ya[5], yb[5];
    {
        const v2f* y0 = (const v2f*)Yn;
        const v2f* y1 = (const v2f*)(Yn + NO_);
#pragma unroll
        for (int i = 0; i < 5; ++i) {
            v2f a = y0[i], b = y1[i];
            ya[i] = pk_f16(a[0], a[1]);
            yb[i] = pk_f16(b[0], b[1]);
        }
    }

    auto step = [&](int t, h2v (&yr)[5], int tl) {
        // x-projection (15 dot2; independent of h -> overlaps LDS latency)
        float xr = 0.f, xz = 0.f, xn = 0.f;
#pragma unroll
        for (int i = 0; i < 5; ++i) {
            FDOT2(xr, wih[0][i], yr[i]);
            FDOT2(xz, wih[1][i], yr[i]);
            FDOT2(xn, wih[2][i], yr[i]);
        }
        // refill yr for t+2 (off critical path)
        {
            const v2f* yp = (const v2f*)(Yn + (size_t)tl * NO_);
#pragma unroll
            for (int i = 0; i < 5; ++i) { v2f v = yp[i]; yr[i] = pk_f16(v[0], v[1]); }
        }
        // h-projection: 8 uniform b128 reads (broadcast), 96 dot2
        float ar = 0.f, az = 0.f, an = 0.f;
        const uint4* hp = (const uint4*)hbuf;
#pragma unroll
        for (int q = 0; q < 8; ++q) {
            uint4 hq = hp[q];
            h2v h0 = __builtin_bit_cast(h2v, hq.x);
            h2v h1 = __builtin_bit_cast(h2v, hq.y);
            h2v h2 = __builtin_bit_cast(h2v, hq.z);
            h2v h3 = __builtin_bit_cast(h2v, hq.w);
            FDOT2(ar, whh[0][4*q+0], h0); FDOT2(az, whh[1][4*q+0], h0); FDOT2(an, whh[2][4*q+0], h0);
            FDOT2(ar, whh[0][4*q+1], h1); FDOT2(az, whh[1][4*q+1], h1); FDOT2(an, whh[2][4*q+1], h1);
            FDOT2(ar, whh[0][4*q+2], h2); FDOT2(az, whh[1][4*q+2], h2); FDOT2(an, whh[2][4*q+2], h2);
            FDOT2(ar, whh[0][4*q+3], h3); FDOT2(az, whh[1][4*q+3], h3); FDOT2(an, whh[2][4*q+3], h3);
        }
        // gates (serial tail; z's sigmoid overlaps r's)
        const float r  = fast_sigmoid(xr + ar + bR);
        const float z  = fast_sigmoid(xz + az + bZ);
        const float nn = fast_tanh(xn + bNx + r * (an + bNh));
        const float h_new = nn + z * (h_own - nn);
        h_own = h_new;
        hbuf[j] = (_Float16)h_new;   // same-wave in-order: visible to next read
        hout[t * HID_] = h_new;      // fire-and-forget, coalesced 256B
    };

    for (int t = 0; t < T_; t += 2) {
        const int t2 = (t + 2 < T_) ? t + 2 : T_ - 1;
        const int t3 = (t + 3 < T_) ? t + 3 : T_ - 1;
        step(t,     ya, t2);
        step(t + 1, yb, t3);
    }
}

// ---------------------------------------------------------------------------
// Phase 2: per-(n,t) dense head + information-form Kalman + log-pdf terms.
// Each block first computes A = H^T inv(C_w), M = A H redundantly (parallel
// Gauss-Jordan over its 256 threads, ~us) -> no separate setup dispatch.
// ---------------------------------------------------------------------------
__global__ __launch_bounds__(256) void post_kernel(
    const float* __restrict__ h_out,  // (N*T,64)
    const float* __restrict__ Y,      // (N,T,NO)
    const float* __restrict__ X,      // (N,T,NS)
    const float* __restrict__ Hm, const float* __restrict__ C_w,
    const float* __restrict__ W_fc, const float* __restrict__ b_fc,
    const float* __restrict__ W_mean, const float* __restrict__ b_mean,
    const float* __restrict__ W_vars, const float* __restrict__ b_vars,
    float* __restrict__ out)
{
    __shared__ float sWfc[DENSE_][HID_];
    __shared__ float sWm[NS_][DENSE_];
    __shared__ float sWv[NS_][DENSE_];
    __shared__ float sA[NS_][NO_];
    __shared__ float sM[NS_][NS_];
    __shared__ float sbfc[DENSE_], sbm[NS_], sbv[NS_];
    __shared__ float wsum[4];
    __shared__ float W[NO_][2 * NO_];
    __shared__ float fcol[NO_];

    const int tid = threadIdx.x;

    // --- per-block A, M via parallel Gauss-Jordan on C_w (10x10 SPD) ---
    if (tid < NO_ * NO_) {
        const int i = tid / NO_, jj = tid % NO_;
        W[i][jj] = C_w[tid];
        W[i][NO_ + jj] = (i == jj) ? 1.f : 0.f;
    }
    __syncthreads();
    for (int p = 0; p < NO_; ++p) {
        const float ip = 1.f / W[p][p];
        __syncthreads();
        if (tid < 2 * NO_) W[p][tid] *= ip;
        __syncthreads();
        if (tid < NO_) fcol[tid] = (tid == p) ? 0.f : W[tid][p];
        __syncthreads();
        if (tid < NO_ * 2 * NO_) {
            const int i = tid / (2 * NO_), jj = tid % (2 * NO_);
            W[i][jj] -= fcol[i] * W[p][jj];
        }
        __syncthreads();
    }
    if (tid < NS_ * NO_) {
        const int s = tid / NO_, o = tid % NO_;
        float acc = 0.f;
        for (int p = 0; p < NO_; ++p) acc += Hm[p * NS_ + s] * W[p][NO_ + o];
        sA[s][o] = acc;
    }
    __syncthreads();
    if (tid < NS_ * NS_) {
        const int s = tid / NS_, q = tid % NS_;
        float acc = 0.f;
        for (int o = 0; o < NO_; ++o) acc += sA[s][o] * Hm[o * NS_ + q];
        sM[s][q] = acc;
    }

    // --- stage dense-head weights ---
    for (int i = tid; i < DENSE_ * HID_; i += blockDim.x)
        sWfc[i / HID_][i % HID_] = W_fc[i];
    for (int i = tid; i < NS_ * DENSE_; i += blockDim.x) {
        sWm[i / DENSE_][i % DENSE_] = W_mean[i];
        sWv[i / DENSE_][i % DENSE_] = W_vars[i];
    }
    if (tid < DENSE_) sbfc[tid] = b_fc[tid];
    if (tid < NS_) { sbm[tid] = b_mean[tid]; sbv[tid] = b_vars[tid]; }
    __syncthreads();

    const int task = blockIdx.x * blockDim.x + tid;
    float contrib = 0.f;
    if (task < N_ * T_) {
        float y[DENSE_];
#pragma unroll
        for (int d = 0; d < DENSE_; ++d) y[d] = sbfc[d];
        const float* hp = h_out + (size_t)task * HID_;
#pragma unroll
        for (int k = 0; k < HID_; k += 4) {
            float4 h4 = *(const float4*)(hp + k);
#pragma unroll
            for (int d = 0; d < DENSE_; ++d) {
                y[d] += sWfc[d][k + 0] * h4.x + sWfc[d][k + 1] * h4.y +
                        sWfc[d][k + 2] * h4.z + sWfc[d][k + 3] * h4.w;
            }
        }
#pragma unroll
        for (int d = 0; d < DENSE_; ++d) y[d] = fmaxf(y[d], 0.f);

        float mu[NS_], vinv[NS_];
#pragma unroll
        for (int s = 0; s < NS_; ++s) {
            float am = sbm[s], av = sbv[s];
#pragma unroll
            for (int d = 0; d < DENSE_; ++d) { am += sWm[s][d] * y[d]; av += sWv[s][d] * y[d]; }
            mu[s] = am;
            float sp = (av > 20.f) ? av : log1pf(__expf(av));  // softplus
            vinv[s] = 1.f / sp;
        }

        const float* yo = Y + (size_t)task * NO_;
        const float* xo = X + (size_t)task * NS_;
        float b[NS_];
#pragma unroll
        for (int s = 0; s < NS_; ++s) {
            float acc = vinv[s] * mu[s];
#pragma unroll
            for (int o = 0; o < NO_; ++o) acc += sA[s][o] * yo[o];
            b[s] = acc;
        }

        // L_inv = M + diag(v^-1), Cholesky
        float L[NS_][NS_];
#pragma unroll
        for (int i = 0; i < NS_; ++i)
#pragma unroll
            for (int jj = 0; jj <= i; ++jj)
                L[i][jj] = sM[i][jj] + ((i == jj) ? vinv[i] : 0.f);
        float ld = 0.f;
        float dinv[NS_];
#pragma unroll
        for (int jj = 0; jj < NS_; ++jj) {
            float s = L[jj][jj];
#pragma unroll
            for (int k = 0; k < jj; ++k) s -= L[jj][k] * L[jj][k];
            float d = sqrtf(s);
            ld += __logf(d);
            float di = 1.f / d;
            dinv[jj] = di;
            L[jj][jj] = d;
#pragma unroll
            for (int i = jj + 1; i < NS_; ++i) {
                float t2 = L[i][jj];
#pragma unroll
                for (int k = 0; k < jj; ++k) t2 -= L[i][k] * L[jj][k];
                L[i][jj] = t2 * di;
            }
        }
        ld *= 2.f;

        float w[NS_];
#pragma unroll
        for (int i = 0; i < NS_; ++i) {
            float s = b[i];
#pragma unroll
            for (int k = 0; k < i; ++k) s -= L[i][k] * w[k];
            w[i] = s * dinv[i];
        }
        float mpost[NS_];
#pragma unroll
        for (int ii = NS_ - 1; ii >= 0; --ii) {
            float s = w[ii];
#pragma unroll
            for (int k = ii + 1; k < NS_; ++k) s -= L[k][ii] * mpost[k];
            mpost[ii] = s * dinv[ii];
        }

        float diff[NS_];
#pragma unroll
        for (int s = 0; s < NS_; ++s) diff[s] = xo[s] - mpost[s];
        float quad = 0.f;
#pragma unroll
        for (int jj = 0; jj < NS_; ++jj) {
            float u = 0.f;
#pragma unroll
            for (int i = jj; i < NS_; ++i) u += L[i][jj] * diff[i];
            quad += u * u;
        }

        contrib = 0.5f * (ld - quad) * (1.0f / (float)N_);
    }

#pragma unroll
    for (int off = 32; off; off >>= 1) contrib += __shfl_down(contrib, off);
    const int wid = tid >> 6;
    if ((tid & 63) == 0) wsum[wid] = contrib;
    __syncthreads();
    if (tid == 0) {
        float s = 0.f;
#pragma unroll
        for (int i = 0; i < 4; ++i) s += wsum[i];
        atomicAdd(out, s);
    }
}

// ---------------------------------------------------------------------------
extern "C" void kernel_launch(void* const* d_in, const int* in_sizes, int n_in,
                              void* d_out, int out_size, void* d_ws, size_t ws_size,
                              hipStream_t stream)
{
    const float* Y      = (const float*)d_in[0];
    const float* X      = (const float*)d_in[1];
    const float* H      = (const float*)d_in[2];
    const float* C_w    = (const float*)d_in[4];
    const float* W_ih   = (const float*)d_in[5];
    const float* W_hh   = (const float*)d_in[6];
    const float* b_ih   = (const float*)d_in[7];
    const float* b_hh   = (const float*)d_in[8];
    const float* W_fc   = (const float*)d_in[9];
    const float* b_fc   = (const float*)d_in[10];
    const float* W_mean = (const float*)d_in[11];
    const float* b_mean = (const float*)d_in[12];
    const float* W_vars = (const float*)d_in[13];
    const float* b_vars = (const float*)d_in[14];
    float* out = (float*)d_out;

    float* h_out = (float*)d_ws;                       // 32.77 MB

    hipLaunchKernelGGL(gru_kernel, dim3(N_), dim3(64), 0, stream,
                       Y, W_ih, W_hh, b_ih, b_hh, h_out, out);
    hipLaunchKernelGGL(post_kernel, dim3((N_ * T_ + 255) / 256), dim3(256), 0, stream,
                       h_out, Y, X, H, C_w, W_fc, b_fc, W_mean, b_mean,
                       W_vars, b_vars, out);
}

// Round 13
// 410.153 us; speedup vs baseline: 1.4529x; 1.2085x over previous
//
#include <hip/hip_runtime.h>
#include <math.h>

// Problem constants (from reference)
#define N_    128
#define T_    1000
#define NS_   10
#define NO_   10
#define HID_  64
#define DENSE_ 32

typedef float v2f __attribute__((ext_vector_type(2)));
typedef float v4f __attribute__((ext_vector_type(4)));
typedef _Float16 h2v __attribute__((ext_vector_type(2)));

// Barrier that waits only on LDS ops (global h_out stores are consumed by a
// later dispatch, never by another wave in-kernel -> no vmcnt drain).
#define LDS_BARRIER() asm volatile("s_waitcnt lgkmcnt(0)\n\ts_barrier" ::: "memory")

// f16 dot2: acc += a[0]*b[0] + a[1]*b[1]  (v_dot2_f32_f16)
#if __has_builtin(__builtin_amdgcn_fdot2)
#define FDOT2(acc, a, b) (acc) = __builtin_amdgcn_fdot2((a), (b), (acc), false)
#else
#define FDOT2(acc, a, b) asm("v_dot2_f32_f16 %0, %1, %2, %0" : "+v"(acc) : "v"(a), "v"(b))
#endif

// pack two f32 -> 2x f16 (v_cvt_pkrtz_f16_f32), bit-cast to our h2v type
__device__ __forceinline__ h2v pk_f16(float a, float b) {
    return __builtin_bit_cast(h2v, __builtin_amdgcn_cvt_pkrtz(a, b));
}

// intra-quad DPP exchange (ctrl is a compile-time immediate)
template <int CTRL>
__device__ __forceinline__ float dpp_mov(float x) {
    int r = __builtin_amdgcn_update_dpp(0, __builtin_bit_cast(int, x),
                                        CTRL, 0xF, 0xF, true);
    return __builtin_bit_cast(float, r);
}
// sum over the 4 lanes of a quad; all 4 lanes get the full sum
__device__ __forceinline__ float quad_sum(float x) {
    x += dpp_mov<0xB1>(x);   // quad_perm [1,0,3,2]
    x += dpp_mov<0x4E>(x);   // quad_perm [2,3,0,1]
    return x;
}

__device__ __forceinline__ float fast_sigmoid(float x) {
    return __builtin_amdgcn_rcpf(1.f + __expf(-x));   // NaN-safe
}
__device__ __forceinline__ float fast_tanh(float x) {
    float e = __expf(2.f * x);
    return 1.f - 2.f * __builtin_amdgcn_rcpf(e + 1.f); // NaN-safe
}

// ---------------------------------------------------------------------------
// Phase 1: GRU scan. 4 waves per sample; lane QUAD owns hidden unit
// unit = w*16 + (l>>2); kh = l&3 covers K-elems [kh*16, kh*16+16).
// Per-lane pinned state: 24 h2v (W_hh) + 5 h2v (W_ih row of gate kh; kh==3
// zero-scaled) = 29 regs — far below the observed ~92-reg allocator ceiling
// that killed r11. Per step: 5 dot2 x-proj (own gate) | 2 uniform
// ds_read_b128 of prev h | 24 dot2 | x routed into partials via 0/1-mask fma
// (biases folded into accumulator INIT constants) | 4 quad-sums via DPP |
// lane-local sigmoid/tanh (all 4 lanes redundant) | kh==0 lane publishes h
// (f16 hbuf + f32 h_out fire-and-forget) | ONE LDS-only barrier.
// Block 0 tid 0 initializes out[0] (gru dispatch precedes post dispatch).
// ---------------------------------------------------------------------------
__global__ __launch_bounds__(256, 1) void gru_kernel(
    const float* __restrict__ Y,     // (N,T,NO)
    const float* __restrict__ W_ih,  // (192,10)
    const float* __restrict__ W_hh,  // (192,64)
    const float* __restrict__ b_ih,
    const float* __restrict__ b_hh,
    float* __restrict__ h_out,       // (N*T,64)
    float* __restrict__ out)
{
    const int n    = blockIdx.x;
    const int tid  = threadIdx.x;    // 0..255
    const int w    = tid >> 6;       // wave 0..3
    const int l    = tid & 63;
    const int unit = w * 16 + (l >> 2);  // hidden unit 0..63
    const int kh   = l & 3;              // K quarter

    if (n == 0 && tid == 0)
        out[0] = 0.5f * (float)NS_ * (float)T_ * logf(2.f * 3.14159265358979323846f);

    // --- W_hh: 3 gate rows, own K-quarter (16 f32 -> 8 h2v each) ---
    h2v whh[3][8];
#pragma unroll
    for (int g = 0; g < 3; ++g) {
        const v4f* wp = (const v4f*)(W_hh + (size_t)(g * HID_ + unit) * HID_ + kh * 16);
#pragma unroll
        for (int q = 0; q < 4; ++q) {
            v4f t = wp[q];
            whh[g][2 * q]     = pk_f16(t.x, t.y);
            whh[g][2 * q + 1] = pk_f16(t.z, t.w);
        }
    }
    // --- W_ih: full row of gate kh (kh==3: zero-scaled duplicate of gate 2) ---
    h2v wihx[5];
    {
        const float s = (kh == 3) ? 0.f : 1.f;
        const int gx = (kh < 3) ? kh : 2;
        const v2f* ip = (const v2f*)(W_ih + (size_t)(gx * HID_ + unit) * NO_);
#pragma unroll
        for (int i = 0; i < 5; ++i) { v2f t = ip[i]; wihx[i] = pk_f16(t[0] * s, t[1] * s); }
    }
    // VOLATILE pin: loads stay in the preamble, values stay resident (29 regs).
#pragma unroll
    for (int g = 0; g < 3; ++g)
#pragma unroll
        for (int k = 0; k < 8; ++k) asm volatile("" : "+v"(whh[g][k]));
#pragma unroll
    for (int i = 0; i < 5; ++i) asm volatile("" : "+v"(wihx[i]));

    // x-routing masks (kh-fixed) and bias-folded accumulator inits (kh==0 lane
    // carries each bias exactly once into the quad sum)
    const float mR = (kh == 0) ? 1.f : 0.f;
    const float mZ = (kh == 1) ? 1.f : 0.f;
    const float mN = (kh >= 2) ? 1.f : 0.f;   // kh==3 contributes 0 (weights zeroed)
    const float cR = (kh == 0) ? (b_ih[unit] + b_hh[unit]) : 0.f;
    const float cZ = (kh == 0) ? (b_ih[HID_ + unit] + b_hh[HID_ + unit]) : 0.f;
    const float cN = (kh == 0) ? b_hh[2 * HID_ + unit] : 0.f;
    const float cX = (kh == 0) ? b_ih[2 * HID_ + unit] : 0.f;

    __shared__ __align__(16) _Float16 hbuf[HID_];
    if (tid < HID_) hbuf[tid] = (_Float16)0.f;
    float h_own = 0.f;
    LDS_BARRIER();

    const float* Yn = Y + (size_t)n * T_ * NO_;
    float* hout = h_out + (size_t)n * T_ * HID_ + unit;

    // depth-2 y prefetch (uniform rows, packed to f16)
    h2v ya[5], yb[5];
    {
        const v2f* y0 = (const v2f*)Yn;
        const v2f* y1 = (const v2f*)(Yn + NO_);
#pragma unroll
        for (int i = 0; i < 5; ++i) {
            v2f a = y0[i], b = y1[i];
            ya[i] = pk_f16(a[0], a[1]);
            yb[i] = pk_f16(b[0], b[1]);
        }
    }

    auto step = [&](int t, h2v (&yr)[5], int tl) {
        // x-projection for this lane's gate (5 dot2)
        float xs = 0.f;
#pragma unroll
        for (int i = 0; i < 5; ++i) FDOT2(xs, wihx[i], yr[i]);
        // refill yr for t+2 (off critical path)
        {
            const v2f* yp = (const v2f*)(Yn + (size_t)tl * NO_);
#pragma unroll
            for (int i = 0; i < 5; ++i) { v2f v = yp[i]; yr[i] = pk_f16(v[0], v[1]); }
        }
        // h-projection: 2 uniform b128 reads of own K-quarter, 24 dot2
        float ar = cR, az = cZ, an = cN, xn = cX;
        const uint4* hp = (const uint4*)(hbuf + kh * 16);
        uint4 hq0 = hp[0], hq1 = hp[1];
        {
            h2v h0 = __builtin_bit_cast(h2v, hq0.x);
            h2v h1 = __builtin_bit_cast(h2v, hq0.y);
            h2v h2 = __builtin_bit_cast(h2v, hq0.z);
            h2v h3 = __builtin_bit_cast(h2v, hq0.w);
            FDOT2(ar, whh[0][0], h0); FDOT2(az, whh[1][0], h0); FDOT2(an, whh[2][0], h0);
            FDOT2(ar, whh[0][1], h1); FDOT2(az, whh[1][1], h1); FDOT2(an, whh[2][1], h1);
            FDOT2(ar, whh[0][2], h2); FDOT2(az, whh[1][2], h2); FDOT2(an, whh[2][2], h2);
            FDOT2(ar, whh[0][3], h3); FDOT2(az, whh[1][3], h3); FDOT2(an, whh[2][3], h3);
        }
        {
            h2v h0 = __builtin_bit_cast(h2v, hq1.x);
            h2v h1 = __builtin_bit_cast(h2v, hq1.y);
            h2v h2 = __builtin_bit_cast(h2v, hq1.z);
            h2v h3 = __builtin_bit_cast(h2v, hq1.w);
            FDOT2(ar, whh[0][4], h0); FDOT2(az, whh[1][4], h0); FDOT2(an, whh[2][4], h0);
            FDOT2(ar, whh[0][5], h1); FDOT2(az, whh[1][5], h1); FDOT2(an, whh[2][5], h1);
            FDOT2(ar, whh[0][6], h2); FDOT2(az, whh[1][6], h2); FDOT2(an, whh[2][6], h2);
            FDOT2(ar, whh[0][7], h3); FDOT2(az, whh[1][7], h3); FDOT2(an, whh[2][7], h3);
        }
        // route x into gate partials (3 fma; masks are lane constants)
        ar = fmaf(xs, mR, ar);
        az = fmaf(xs, mZ, az);
        xn = fmaf(xs, mN, xn);
        // quad combine (all 4 lanes end with full sums)
        ar = quad_sum(ar);
        az = quad_sum(az);
        an = quad_sum(an);
        xn = quad_sum(xn);
        // gates (lane-local, redundant across quad)
        const float r  = fast_sigmoid(ar);
        const float z  = fast_sigmoid(az);
        const float nn = fast_tanh(xn + r * an);
        const float h_new = nn + z * (h_own - nn);
        h_own = h_new;
        if (kh == 0) {
            hbuf[unit] = (_Float16)h_new;   // next-step state (f16)
            hout[t * HID_] = h_new;         // fire-and-forget (f32, 64B/wave)
        }
        LDS_BARRIER();
    };

    for (int t = 0; t < T_; t += 2) {
        const int t2 = (t + 2 < T_) ? t + 2 : T_ - 1;
        const int t3 = (t + 3 < T_) ? t + 3 : T_ - 1;
        step(t,     ya, t2);
        step(t + 1, yb, t3);
    }
}

// ---------------------------------------------------------------------------
// Phase 2: per-(n,t) dense head + information-form Kalman + log-pdf terms.
// Each block computes A = H^T inv(C_w), M = A H redundantly (parallel GJ).
// ---------------------------------------------------------------------------
__global__ __launch_bounds__(256) void post_kernel(
    const float* __restrict__ h_out,  // (N*T,64)
    const float* __restrict__ Y,      // (N,T,NO)
    const float* __restrict__ X,      // (N,T,NS)
    const float* __restrict__ Hm, const float* __restrict__ C_w,
    const float* __restrict__ W_fc, const float* __restrict__ b_fc,
    const float* __restrict__ W_mean, const float* __restrict__ b_mean,
    const float* __restrict__ W_vars, const float* __restrict__ b_vars,
    float* __restrict__ out)
{
    __shared__ float sWfc[DENSE_][HID_];
    __shared__ float sWm[NS_][DENSE_];
    __shared__ float sWv[NS_][DENSE_];
    __shared__ float sA[NS_][NO_];
    __shared__ float sM[NS_][NS_];
    __shared__ float sbfc[DENSE_], sbm[NS_], sbv[NS_];
    __shared__ float wsum[4];
    __shared__ float W[NO_][2 * NO_];
    __shared__ float fcol[NO_];

    const int tid = threadIdx.x;

    // --- per-block A, M via parallel Gauss-Jordan on C_w (10x10 SPD) ---
    if (tid < NO_ * NO_) {
        const int i = tid / NO_, jj = tid % NO_;
        W[i][jj] = C_w[tid];
        W[i][NO_ + jj] = (i == jj) ? 1.f : 0.f;
    }
    __syncthreads();
    for (int p = 0; p < NO_; ++p) {
        const float ip = 1.f / W[p][p];
        __syncthreads();
        if (tid < 2 * NO_) W[p][tid] *= ip;
        __syncthreads();
        if (tid < NO_) fcol[tid] = (tid == p) ? 0.f : W[tid][p];
        __syncthreads();
        if (tid < NO_ * 2 * NO_) {
            const int i = tid / (2 * NO_), jj = tid % (2 * NO_);
            W[i][jj] -= fcol[i] * W[p][jj];
        }
        __syncthreads();
    }
    if (tid < NS_ * NO_) {
        const int s = tid / NO_, o = tid % NO_;
        float acc = 0.f;
        for (int p = 0; p < NO_; ++p) acc += Hm[p * NS_ + s] * W[p][NO_ + o];
        sA[s][o] = acc;
    }
    __syncthreads();
    if (tid < NS_ * NS_) {
        const int s = tid / NS_, q = tid % NS_;
        float acc = 0.f;
        for (int o = 0; o < NO_; ++o) acc += sA[s][o] * Hm[o * NS_ + q];
        sM[s][q] = acc;
    }

    // --- stage dense-head weights ---
    for (int i = tid; i < DENSE_ * HID_; i += blockDim.x)
        sWfc[i / HID_][i % HID_] = W_fc[i];
    for (int i = tid; i < NS_ * DENSE_; i += blockDim.x) {
        sWm[i / DENSE_][i % DENSE_] = W_mean[i];
        sWv[i / DENSE_][i % DENSE_] = W_vars[i];
    }
    if (tid < DENSE_) sbfc[tid] = b_fc[tid];
    if (tid < NS_) { sbm[tid] = b_mean[tid]; sbv[tid] = b_vars[tid]; }
    __syncthreads();

    const int task = blockIdx.x * blockDim.x + tid;
    float contrib = 0.f;
    if (task < N_ * T_) {
        float y[DENSE_];
#pragma unroll
        for (int d = 0; d < DENSE_; ++d) y[d] = sbfc[d];
        const float* hp = h_out + (size_t)task * HID_;
#pragma unroll
        for (int k = 0; k < HID_; k += 4) {
            float4 h4 = *(const float4*)(hp + k);
#pragma unroll
            for (int d = 0; d < DENSE_; ++d) {
                y[d] += sWfc[d][k + 0] * h4.x + sWfc[d][k + 1] * h4.y +
                        sWfc[d][k + 2] * h4.z + sWfc[d][k + 3] * h4.w;
            }
        }
#pragma unroll
        for (int d = 0; d < DENSE_; ++d) y[d] = fmaxf(y[d], 0.f);

        float mu[NS_], vinv[NS_];
#pragma unroll
        for (int s = 0; s < NS_; ++s) {
            float am = sbm[s], av = sbv[s];
#pragma unroll
            for (int d = 0; d < DENSE_; ++d) { am += sWm[s][d] * y[d]; av += sWv[s][d] * y[d]; }
            mu[s] = am;
            float sp = (av > 20.f) ? av : log1pf(__expf(av));  // softplus
            vinv[s] = 1.f / sp;
        }

        const float* yo = Y + (size_t)task * NO_;
        const float* xo = X + (size_t)task * NS_;
        float b[NS_];
#pragma unroll
        for (int s = 0; s < NS_; ++s) {
            float acc = vinv[s] * mu[s];
#pragma unroll
            for (int o = 0; o < NO_; ++o) acc += sA[s][o] * yo[o];
            b[s] = acc;
        }

        // L_inv = M + diag(v^-1), Cholesky
        float L[NS_][NS_];
#pragma unroll
        for (int i = 0; i < NS_; ++i)
#pragma unroll
            for (int jj = 0; jj <= i; ++jj)
                L[i][jj] = sM[i][jj] + ((i == jj) ? vinv[i] : 0.f);
        float ld = 0.f;
        float dinv[NS_];
#pragma unroll
        for (int jj = 0; jj < NS_; ++jj) {
            float s = L[jj][jj];
#pragma unroll
            for (int k = 0; k < jj; ++k) s -= L[jj][k] * L[jj][k];
            float d = sqrtf(s);
            ld += __logf(d);
            float di = 1.f / d;
            dinv[jj] = di;
            L[jj][jj] = d;
#pragma unroll
            for (int i = jj + 1; i < NS_; ++i) {
                float t2 = L[i][jj];
#pragma unroll
                for (int k = 0; k < jj; ++k) t2 -= L[i][k] * L[jj][k];
                L[i][jj] = t2 * di;
            }
        }
        ld *= 2.f;

        float w[NS_];
#pragma unroll
        for (int i = 0; i < NS_; ++i) {
            float s = b[i];
#pragma unroll
            for (int k = 0; k < i; ++k) s -= L[i][k] * w[k];
            w[i] = s * dinv[i];
        }
        float mpost[NS_];
#pragma unroll
        for (int ii = NS_ - 1; ii >= 0; --ii) {
            float s = w[ii];
#pragma unroll
            for (int k = ii + 1; k < NS_; ++k) s -= L[k][ii] * mpost[k];
            mpost[ii] = s * dinv[ii];
        }

        float diff[NS_];
#pragma unroll
        for (int s = 0; s < NS_; ++s) diff[s] = xo[s] - mpost[s];
        float quad = 0.f;
#pragma unroll
        for (int jj = 0; jj < NS_; ++jj) {
            float u = 0.f;
#pragma unroll
            for (int i = jj; i < NS_; ++i) u += L[i][jj] * diff[i];
            quad += u * u;
        }

        contrib = 0.5f * (ld - quad) * (1.0f / (float)N_);
    }

#pragma unroll
    for (int off = 32; off; off >>= 1) contrib += __shfl_down(contrib, off);
    const int wid = tid >> 6;
    if ((tid & 63) == 0) wsum[wid] = contrib;
    __syncthreads();
    if (tid == 0) {
        float s = 0.f;
#pragma unroll
        for (int i = 0; i < 4; ++i) s += wsum[i];
        atomicAdd(out, s);
    }
}

// ---------------------------------------------------------------------------
extern "C" void kernel_launch(void* const* d_in, const int* in_sizes, int n_in,
                              void* d_out, int out_size, void* d_ws, size_t ws_size,
                              hipStream_t stream)
{
    const float* Y      = (const float*)d_in[0];
    const float* X      = (const float*)d_in[1];
    const float* H      = (const float*)d_in[2];
    const float* C_w    = (const float*)d_in[4];
    const float* W_ih   = (const float*)d_in[5];
    const float* W_hh   = (const float*)d_in[6];
    const float* b_ih   = (const float*)d_in[7];
    const float* b_hh   = (const float*)d_in[8];
    const float* W_fc   = (const float*)d_in[9];
    const float* b_fc   = (const float*)d_in[10];
    const float* W_mean = (const float*)d_in[11];
    const float* b_mean = (const float*)d_in[12];
    const float* W_vars = (const float*)d_in[13];
    const float* b_vars = (const float*)d_in[14];
    float* out = (float*)d_out;

    float* h_out = (float*)d_ws;                       // 32.77 MB

    hipLaunchKernelGGL(gru_kernel, dim3(N_), dim3(256), 0, stream,
                       Y, W_ih, W_hh, b_ih, b_hh, h_out, out);
    hipLaunchKernelGGL(post_kernel, dim3((N_ * T_ + 255) / 256), dim3(256), 0, stream,
                       h_out, Y, X, H, C_w, W_fc, b_fc, W_mean, b_mean,
                       W_vars, b_vars, out);
}

// Round 14
// 313.363 us; speedup vs baseline: 1.9016x; 1.3089x over previous
//
#include <hip/hip_runtime.h>
#include <math.h>

// Problem constants (from reference)
#define N_    128
#define T_    1000
#define NS_   10
#define NO_   10
#define HID_  64
#define DENSE_ 32

typedef float v2f __attribute__((ext_vector_type(2)));
typedef float v4f __attribute__((ext_vector_type(4)));
typedef _Float16 h2v __attribute__((ext_vector_type(2)));

// Barrier that waits only on LDS ops (global h_out stores are consumed by a
// later dispatch, never by another wave in-kernel -> no vmcnt drain).
#define LDS_BARRIER() asm volatile("s_waitcnt lgkmcnt(0)\n\ts_barrier" ::: "memory")

// f16 dot2: acc += a[0]*b[0] + a[1]*b[1]  (v_dot2_f32_f16)
#if __has_builtin(__builtin_amdgcn_fdot2)
#define FDOT2(acc, a, b) (acc) = __builtin_amdgcn_fdot2((a), (b), (acc), false)
#else
#define FDOT2(acc, a, b) asm("v_dot2_f32_f16 %0, %1, %2, %0" : "+v"(acc) : "v"(a), "v"(b))
#endif

// pack two f32 -> 2x f16 (v_cvt_pkrtz_f16_f32), bit-cast to our h2v type
__device__ __forceinline__ h2v pk_f16(float a, float b) {
    return __builtin_bit_cast(h2v, __builtin_amdgcn_cvt_pkrtz(a, b));
}

// intra-quad DPP exchange (ctrl is a compile-time immediate)
template <int CTRL>
__device__ __forceinline__ float dpp_mov(float x) {
    int r = __builtin_amdgcn_update_dpp(0, __builtin_bit_cast(int, x),
                                        CTRL, 0xF, 0xF, true);
    return __builtin_bit_cast(float, r);
}
// sum over the 4 lanes of a quad; all 4 lanes get the full sum
__device__ __forceinline__ float quad_sum(float x) {
    x += dpp_mov<0xB1>(x);   // quad_perm [1,0,3,2]
    x += dpp_mov<0x4E>(x);   // quad_perm [2,3,0,1]
    return x;
}

__device__ __forceinline__ float fast_sigmoid(float x) {
    return __builtin_amdgcn_rcpf(1.f + __expf(-x));   // NaN-safe
}
__device__ __forceinline__ float fast_tanh(float x) {
    float e = __expf(2.f * x);
    return 1.f - 2.f * __builtin_amdgcn_rcpf(e + 1.f); // NaN-safe
}

// ---------------------------------------------------------------------------
// Phase 1: GRU scan. 4 waves per sample; lane QUAD owns hidden unit
// unit = w*16 + (l>>2); kh = l&3 covers K-elems [kh*16, kh*16+16).
// r13 lesson: per-step global y loads exposed HBM/L3 latency on the critical
// path (cold 447 vs warm 368 us). Fix: stage the sample's WHOLE Y (40KB f32
// -> 20KB f16) into LDS up front; the loop reads y via uniform ds_read_b32
// issued at the END of the previous step (drained by the barrier's lgkmcnt).
// Loop has ZERO global loads; only the fire-and-forget h_out store remains.
// Weights: 24 h2v W_hh + 5 h2v W_ih per lane, volatile-pinned (r13: VGPR=36,
// no spill, no per-step refetch). One LDS-only barrier per step.
// ---------------------------------------------------------------------------
__global__ __launch_bounds__(256, 1) void gru_kernel(
    const float* __restrict__ Y,     // (N,T,NO)
    const float* __restrict__ W_ih,  // (192,10)
    const float* __restrict__ W_hh,  // (192,64)
    const float* __restrict__ b_ih,
    const float* __restrict__ b_hh,
    float* __restrict__ h_out,       // (N*T,64)
    float* __restrict__ out)
{
    const int n    = blockIdx.x;
    const int tid  = threadIdx.x;    // 0..255
    const int w    = tid >> 6;       // wave 0..3
    const int l    = tid & 63;
    const int unit = w * 16 + (l >> 2);  // hidden unit 0..63
    const int kh   = l & 3;              // K quarter

    if (n == 0 && tid == 0)
        out[0] = 0.5f * (float)NS_ * (float)T_ * logf(2.f * 3.14159265358979323846f);

    // --- LDS: full-sample y (f16) + hidden state ---
    __shared__ __align__(16) h2v ylds[T_ * NO_ / 2];   // 5000 h2v = 20 KB
    __shared__ __align__(16) _Float16 hbuf[HID_];

    const float* Yn = Y + (size_t)n * T_ * NO_;
    // stage Y: coalesced float2 loads -> f16 pairs (row t = h2v [5t,5t+5))
    {
        const v2f* src = (const v2f*)Yn;
#pragma unroll 4
        for (int i = tid; i < T_ * NO_ / 2; i += 256) {
            v2f v = src[i];
            ylds[i] = pk_f16(v[0], v[1]);
        }
    }

    // --- W_hh: 3 gate rows, own K-quarter (16 f32 -> 8 h2v each) ---
    h2v whh[3][8];
#pragma unroll
    for (int g = 0; g < 3; ++g) {
        const v4f* wp = (const v4f*)(W_hh + (size_t)(g * HID_ + unit) * HID_ + kh * 16);
#pragma unroll
        for (int q = 0; q < 4; ++q) {
            v4f t = wp[q];
            whh[g][2 * q]     = pk_f16(t.x, t.y);
            whh[g][2 * q + 1] = pk_f16(t.z, t.w);
        }
    }
    // --- W_ih: full row of gate kh (kh==3: zero-scaled duplicate of gate 2) ---
    h2v wihx[5];
    {
        const float s = (kh == 3) ? 0.f : 1.f;
        const int gx = (kh < 3) ? kh : 2;
        const v2f* ip = (const v2f*)(W_ih + (size_t)(gx * HID_ + unit) * NO_);
#pragma unroll
        for (int i = 0; i < 5; ++i) { v2f t = ip[i]; wihx[i] = pk_f16(t[0] * s, t[1] * s); }
    }
    // VOLATILE pin: loads stay in the preamble, values stay resident.
#pragma unroll
    for (int g = 0; g < 3; ++g)
#pragma unroll
        for (int k = 0; k < 8; ++k) asm volatile("" : "+v"(whh[g][k]));
#pragma unroll
    for (int i = 0; i < 5; ++i) asm volatile("" : "+v"(wihx[i]));

    // x-routing masks (kh-fixed) and bias-folded accumulator inits
    const float mR = (kh == 0) ? 1.f : 0.f;
    const float mZ = (kh == 1) ? 1.f : 0.f;
    const float mN = (kh >= 2) ? 1.f : 0.f;
    const float cR = (kh == 0) ? (b_ih[unit] + b_hh[unit]) : 0.f;
    const float cZ = (kh == 0) ? (b_ih[HID_ + unit] + b_hh[HID_ + unit]) : 0.f;
    const float cN = (kh == 0) ? b_hh[2 * HID_ + unit] : 0.f;
    const float cX = (kh == 0) ? b_ih[2 * HID_ + unit] : 0.f;

    if (tid < HID_) hbuf[tid] = (_Float16)0.f;
    float h_own = 0.f;
    __syncthreads();   // staging + hbuf visible to all waves

    float* hout = h_out + (size_t)n * T_ * HID_ + unit;

    // prologue: y row 0 into registers (uniform LDS reads)
    h2v y0 = ylds[0], y1 = ylds[1], y2 = ylds[2], y3 = ylds[3], y4 = ylds[4];

    for (int t = 0; t < T_; ++t) {
        // x-projection from preloaded registers (overlaps hbuf read latency)
        float xs = 0.f;
        FDOT2(xs, wihx[0], y0); FDOT2(xs, wihx[1], y1); FDOT2(xs, wihx[2], y2);
        FDOT2(xs, wihx[3], y3); FDOT2(xs, wihx[4], y4);

        // h-projection: 2 uniform b128 reads of own K-quarter, 24 dot2
        float ar = cR, az = cZ, an = cN, xn = cX;
        const uint4* hp = (const uint4*)(hbuf + kh * 16);
        uint4 hq0 = hp[0], hq1 = hp[1];
        {
            h2v h0 = __builtin_bit_cast(h2v, hq0.x);
            h2v h1 = __builtin_bit_cast(h2v, hq0.y);
            h2v h2 = __builtin_bit_cast(h2v, hq0.z);
            h2v h3 = __builtin_bit_cast(h2v, hq0.w);
            FDOT2(ar, whh[0][0], h0); FDOT2(az, whh[1][0], h0); FDOT2(an, whh[2][0], h0);
            FDOT2(ar, whh[0][1], h1); FDOT2(az, whh[1][1], h1); FDOT2(an, whh[2][1], h1);
            FDOT2(ar, whh[0][2], h2); FDOT2(az, whh[1][2], h2); FDOT2(an, whh[2][2], h2);
            FDOT2(ar, whh[0][3], h3); FDOT2(az, whh[1][3], h3); FDOT2(an, whh[2][3], h3);
        }
        {
            h2v h0 = __builtin_bit_cast(h2v, hq1.x);
            h2v h1 = __builtin_bit_cast(h2v, hq1.y);
            h2v h2 = __builtin_bit_cast(h2v, hq1.z);
            h2v h3 = __builtin_bit_cast(h2v, hq1.w);
            FDOT2(ar, whh[0][4], h0); FDOT2(az, whh[1][4], h0); FDOT2(an, whh[2][4], h0);
            FDOT2(ar, whh[0][5], h1); FDOT2(az, whh[1][5], h1); FDOT2(an, whh[2][5], h1);
            FDOT2(ar, whh[0][6], h2); FDOT2(az, whh[1][6], h2); FDOT2(an, whh[2][6], h2);
            FDOT2(ar, whh[0][7], h3); FDOT2(az, whh[1][7], h3); FDOT2(an, whh[2][7], h3);
        }
        // route x into gate partials (3 fma; masks are lane constants)
        ar = fmaf(xs, mR, ar);
        az = fmaf(xs, mZ, az);
        xn = fmaf(xs, mN, xn);
        // quad combine (all 4 lanes end with full sums)
        ar = quad_sum(ar);
        az = quad_sum(az);
        an = quad_sum(an);
        xn = quad_sum(xn);
        // gates (lane-local, redundant across quad)
        const float r  = fast_sigmoid(ar);
        const float z  = fast_sigmoid(az);
        const float nn = fast_tanh(xn + r * an);
        const float h_new = nn + z * (h_own - nn);
        h_own = h_new;
        if (kh == 0) {
            hbuf[unit] = (_Float16)h_new;   // next-step state (f16)
            hout[t * HID_] = h_new;         // fire-and-forget (f32)
        }
        // prefetch y row t+1 (uniform LDS reads; drained by barrier lgkmcnt)
        {
            const h2v* yrow = ylds + 5 * ((t + 1 < T_) ? t + 1 : t);
            y0 = yrow[0]; y1 = yrow[1]; y2 = yrow[2]; y3 = yrow[3]; y4 = yrow[4];
        }
        LDS_BARRIER();
    }
}

// ---------------------------------------------------------------------------
// Phase 2: per-(n,t) dense head + information-form Kalman + log-pdf terms.
// Each block computes A = H^T inv(C_w), M = A H redundantly (parallel GJ).
// ---------------------------------------------------------------------------
__global__ __launch_bounds__(256) void post_kernel(
    const float* __restrict__ h_out,  // (N*T,64)
    const float* __restrict__ Y,      // (N,T,NO)
    const float* __restrict__ X,      // (N,T,NS)
    const float* __restrict__ Hm, const float* __restrict__ C_w,
    const float* __restrict__ W_fc, const float* __restrict__ b_fc,
    const float* __restrict__ W_mean, const float* __restrict__ b_mean,
    const float* __restrict__ W_vars, const float* __restrict__ b_vars,
    float* __restrict__ out)
{
    __shared__ float sWfc[DENSE_][HID_];
    __shared__ float sWm[NS_][DENSE_];
    __shared__ float sWv[NS_][DENSE_];
    __shared__ float sA[NS_][NO_];
    __shared__ float sM[NS_][NS_];
    __shared__ float sbfc[DENSE_], sbm[NS_], sbv[NS_];
    __shared__ float wsum[4];
    __shared__ float W[NO_][2 * NO_];
    __shared__ float fcol[NO_];

    const int tid = threadIdx.x;

    // --- per-block A, M via parallel Gauss-Jordan on C_w (10x10 SPD) ---
    if (tid < NO_ * NO_) {
        const int i = tid / NO_, jj = tid % NO_;
        W[i][jj] = C_w[tid];
        W[i][NO_ + jj] = (i == jj) ? 1.f : 0.f;
    }
    __syncthreads();
    for (int p = 0; p < NO_; ++p) {
        const float ip = 1.f / W[p][p];
        __syncthreads();
        if (tid < 2 * NO_) W[p][tid] *= ip;
        __syncthreads();
        if (tid < NO_) fcol[tid] = (tid == p) ? 0.f : W[tid][p];
        __syncthreads();
        if (tid < NO_ * 2 * NO_) {
            const int i = tid / (2 * NO_), jj = tid % (2 * NO_);
            W[i][jj] -= fcol[i] * W[p][jj];
        }
        __syncthreads();
    }
    if (tid < NS_ * NO_) {
        const int s = tid / NO_, o = tid % NO_;
        float acc = 0.f;
        for (int p = 0; p < NO_; ++p) acc += Hm[p * NS_ + s] * W[p][NO_ + o];
        sA[s][o] = acc;
    }
    __syncthreads();
    if (tid < NS_ * NS_) {
        const int s = tid / NS_, q = tid % NS_;
        float acc = 0.f;
        for (int o = 0; o < NO_; ++o) acc += sA[s][o] * Hm[o * NS_ + q];
        sM[s][q] = acc;
    }

    // --- stage dense-head weights ---
    for (int i = tid; i < DENSE_ * HID_; i += blockDim.x)
        sWfc[i / HID_][i % HID_] = W_fc[i];
    for (int i = tid; i < NS_ * DENSE_; i += blockDim.x) {
        sWm[i / DENSE_][i % DENSE_] = W_mean[i];
        sWv[i / DENSE_][i % DENSE_] = W_vars[i];
    }
    if (tid < DENSE_) sbfc[tid] = b_fc[tid];
    if (tid < NS_) { sbm[tid] = b_mean[tid]; sbv[tid] = b_vars[tid]; }
    __syncthreads();

    const int task = blockIdx.x * blockDim.x + tid;
    float contrib = 0.f;
    if (task < N_ * T_) {
        float y[DENSE_];
#pragma unroll
        for (int d = 0; d < DENSE_; ++d) y[d] = sbfc[d];
        const float* hp = h_out + (size_t)task * HID_;
#pragma unroll
        for (int k = 0; k < HID_; k += 4) {
            float4 h4 = *(const float4*)(hp + k);
#pragma unroll
            for (int d = 0; d < DENSE_; ++d) {
                y[d] += sWfc[d][k + 0] * h4.x + sWfc[d][k + 1] * h4.y +
                        sWfc[d][k + 2] * h4.z + sWfc[d][k + 3] * h4.w;
            }
        }
#pragma unroll
        for (int d = 0; d < DENSE_; ++d) y[d] = fmaxf(y[d], 0.f);

        float mu[NS_], vinv[NS_];
#pragma unroll
        for (int s = 0; s < NS_; ++s) {
            float am = sbm[s], av = sbv[s];
#pragma unroll
            for (int d = 0; d < DENSE_; ++d) { am += sWm[s][d] * y[d]; av += sWv[s][d] * y[d]; }
            mu[s] = am;
            float sp = (av > 20.f) ? av : log1pf(__expf(av));  // softplus
            vinv[s] = 1.f / sp;
        }

        const float* yo = Y + (size_t)task * NO_;
        const float* xo = X + (size_t)task * NS_;
        float b[NS_];
#pragma unroll
        for (int s = 0; s < NS_; ++s) {
            float acc = vinv[s] * mu[s];
#pragma unroll
            for (int o = 0; o < NO_; ++o) acc += sA[s][o] * yo[o];
            b[s] = acc;
        }

        // L_inv = M + diag(v^-1), Cholesky
        float L[NS_][NS_];
#pragma unroll
        for (int i = 0; i < NS_; ++i)
#pragma unroll
            for (int jj = 0; jj <= i; ++jj)
                L[i][jj] = sM[i][jj] + ((i == jj) ? vinv[i] : 0.f);
        float ld = 0.f;
        float dinv[NS_];
#pragma unroll
        for (int jj = 0; jj < NS_; ++jj) {
            float s = L[jj][jj];
#pragma unroll
            for (int k = 0; k < jj; ++k) s -= L[jj][k] * L[jj][k];
            float d = sqrtf(s);
            ld += __logf(d);
            float di = 1.f / d;
            dinv[jj] = di;
            L[jj][jj] = d;
#pragma unroll
            for (int i = jj + 1; i < NS_; ++i) {
                float t2 = L[i][jj];
#pragma unroll
                for (int k = 0; k < jj; ++k) t2 -= L[i][k] * L[jj][k];
                L[i][jj] = t2 * di;
            }
        }
        ld *= 2.f;

        float w[NS_];
#pragma unroll
        for (int i = 0; i < NS_; ++i) {
            float s = b[i];
#pragma unroll
            for (int k = 0; k < i; ++k) s -= L[i][k] * w[k];
            w[i] = s * dinv[i];
        }
        float mpost[NS_];
#pragma unroll
        for (int ii = NS_ - 1; ii >= 0; --ii) {
            float s = w[ii];
#pragma unroll
            for (int k = ii + 1; k < NS_; ++k) s -= L[k][ii] * mpost[k];
            mpost[ii] = s * dinv[ii];
        }

        float diff[NS_];
#pragma unroll
        for (int s = 0; s < NS_; ++s) diff[s] = xo[s] - mpost[s];
        float quad = 0.f;
#pragma unroll
        for (int jj = 0; jj < NS_; ++jj) {
            float u = 0.f;
#pragma unroll
            for (int i = jj; i < NS_; ++i) u += L[i][jj] * diff[i];
            quad += u * u;
        }

        contrib = 0.5f * (ld - quad) * (1.0f / (float)N_);
    }

#pragma unroll
    for (int off = 32; off; off >>= 1) contrib += __shfl_down(contrib, off);
    const int wid = tid >> 6;
    if ((tid & 63) == 0) wsum[wid] = contrib;
    __syncthreads();
    if (tid == 0) {
        float s = 0.f;
#pragma unroll
        for (int i = 0; i < 4; ++i) s += wsum[i];
        atomicAdd(out, s);
    }
}

// ---------------------------------------------------------------------------
extern "C" void kernel_launch(void* const* d_in, const int* in_sizes, int n_in,
                              void* d_out, int out_size, void* d_ws, size_t ws_size,
                              hipStream_t stream)
{
    const float* Y      = (const float*)d_in[0];
    const float* X      = (const float*)d_in[1];
    const float* H      = (const float*)d_in[2];
    const float* C_w    = (const float*)d_in[4];
    const float* W_ih   = (const float*)d_in[5];
    const float* W_hh   = (const float*)d_in[6];
    const float* b_ih   = (const float*)d_in[7];
    const float* b_hh   = (const float*)d_in[8];
    const float* W_fc   = (const float*)d_in[9];
    const float* b_fc   = (const float*)d_in[10];
    const float* W_mean = (const float*)d_in[11];
    const float* b_mean = (const float*)d_in[12];
    const float* W_vars = (const float*)d_in[13];
    const float* b_vars = (const float*)d_in[14];
    float* out = (float*)d_out;

    float* h_out = (float*)d_ws;                       // 32.77 MB

    hipLaunchKernelGGL(gru_kernel, dim3(N_), dim3(256), 0, stream,
                       Y, W_ih, W_hh, b_ih, b_hh, h_out, out);
    hipLaunchKernelGGL(post_kernel, dim3((N_ * T_ + 255) / 256), dim3(256), 0, stream,
                       h_out, Y, X, H, C_w, W_fc, b_fc, W_mean, b_mean,
                       W_vars, b_vars, out);
}